// Round 17
// baseline (958.803 us; speedup 1.0000x reference)
//
#include <hip/hip_runtime.h>

// ---------------- problem constants ----------------
#define H 1024
#define W 1024
#define HW (H*W)
#define NB 8            // batch
#define NIMG 16         // gt batch (0..7) + pred-fg batch (8..15)
#define BORDER 25
#define KLEN 51
#define SKEL_TILES 2400     // 10 x 15 x 16
#define DONE_PER_IMG 150    // 10 x 15
#define BLUR_BLOCKS 512     // 16 strips x 4 quarters x 8 pairs

// Unnormalized Gaussian weights g[k] = exp(-(k-25)^2/200), k=0..50 (sigma=10).
__device__ __constant__ float GW[KLEN] = {
  0.04393693f, 0.05613476f, 0.07100535f, 0.08892162f, 0.11025053f,
  0.13533528f, 0.16447446f, 0.19789869f, 0.23574608f, 0.27803730f,
  0.32465247f, 0.37531110f, 0.42955736f, 0.48675226f, 0.54607442f,
  0.60653066f, 0.66697681f, 0.72614904f, 0.78270454f, 0.83527021f,
  0.88249690f, 0.92311635f, 0.95599748f, 0.98019867f, 0.99501248f,
  1.00000000f,
  0.99501248f, 0.98019867f, 0.95599748f, 0.92311635f, 0.88249690f,
  0.83527021f, 0.78270454f, 0.72614904f, 0.66697681f, 0.60653066f,
  0.54607442f, 0.48675226f, 0.42955736f, 0.37531110f, 0.32465247f,
  0.27803730f, 0.23574608f, 0.19789869f, 0.16447446f, 0.13533528f,
  0.11025053f, 0.08892162f, 0.07100535f, 0.05613476f, 0.04393693f
};

__device__ inline float m3n(float a,float b,float c){
  float d; asm("v_min3_f32 %0, %1, %2, %3" : "=v"(d) : "v"(a), "v"(b), "v"(c));
  return d;
}
__device__ inline float m3x(float a,float b,float c){
  float d; asm("v_max3_f32 %0, %1, %2, %3" : "=v"(d) : "v"(a), "v"(b), "v"(c));
  return d;
}
__device__ inline float dpp_shr1(float x){
  return __int_as_float(__builtin_amdgcn_mov_dpp(__float_as_int(x), 0x138, 0xf, 0xf, true));
}
__device__ inline float dpp_shl1(float x){
  return __int_as_float(__builtin_amdgcn_mov_dpp(__float_as_int(x), 0x130, 0xf, 0xf, true));
}
__device__ inline float4 hmin4(float4 C){
  float Lw = dpp_shr1(C.w);
  float Rx = dpp_shl1(C.x);
  float4 h;
  h.x=m3n(Lw ,C.x,C.y); h.y=m3n(C.x,C.y,C.z);
  h.z=m3n(C.y,C.z,C.w); h.w=m3n(C.z,C.w,Rx );
  return h;
}
__device__ inline float4 hmax4(float4 C){
  float Lw = dpp_shr1(C.w);
  float Rx = dpp_shl1(C.x);
  float4 h;
  h.x=m3x(Lw ,C.x,C.y); h.y=m3x(C.x,C.y,C.z);
  h.z=m3x(C.y,C.z,C.w); h.w=m3x(C.z,C.w,Rx );
  return h;
}
__device__ inline float4 vmin3(float4 a,float4 b,float4 c){
  float4 o; o.x=m3n(a.x,b.x,c.x); o.y=m3n(a.y,b.y,c.y);
            o.z=m3n(a.z,b.z,c.z); o.w=m3n(a.w,b.w,c.w); return o;
}
__device__ inline float4 vmax3(float4 a,float4 b,float4 c){
  float4 o; o.x=m3x(a.x,b.x,c.x); o.y=m3x(a.y,b.y,c.y);
            o.z=m3x(a.z,b.z,c.z); o.w=m3x(a.w,b.w,c.w); return o;
}
__device__ inline float4 msk4(float4 e, bool v){
  constexpr float NINF = -__builtin_huge_valf();
  float4 o; o.x=v?e.x:NINF; o.y=v?e.y:NINF; o.z=v?e.z:NINF; o.w=v?e.w:NINF;
  return o;
}

// shared-memory union: skel exchange buffer / blur ring (phases barrier-separated)
struct BD { float hbg[128][64]; float hbp[128][64]; double rbuf[12]; };
union ShmU {
  float4 xch[2][32][32];   // 32 KB (skel)
  BD bd;                   // 64.5 KB (blur)
};

__device__ inline unsigned ldrlx(unsigned* p){
  return __hip_atomic_load(p, __ATOMIC_RELAXED, __HIP_MEMORY_SCOPE_AGENT);
}

// ---------------- skel tile (round-16 body, parameterized) ----------------
__device__ __attribute__((noinline))
void skel_tile(int tile, const float* __restrict__ pred, const float* __restrict__ targ,
               float* __restrict__ S, unsigned* __restrict__ done, ShmU& shm)
{
  constexpr float PINF = __builtin_huge_valf();
  const int img = tile / DONE_PER_IMG;
  const int rr_ = tile - img*DONE_PER_IMG;
  const int bx = rr_ % 10;
  const int by = rr_ / 10;

  const int gx0 = bx*104 - 12, gy0 = by*72 - 12;
  const int tid = threadIdx.x;
  const int g = tid >> 5;
  const int j = tid & 31;
  const int wid = tid >> 6;
  const int R0 = 6*g;
  const int gxb = gx0 + 4*j;
  const bool xok = ((unsigned)gxb < (unsigned)W);
  const bool cenj = (j >= 3) && (j < 29);
  const bool allok = (gx0 >= 0) && (gx0 + 128 <= W) && (gy0 >= 0) && (gy0 + 96 <= H);
  const bool cwave = (wid >= 1) && (wid <= 6);
  const int ixm = (g>0)  ? 2*g-1 : 0;
  const int ixp = (g<15) ? 2*g+2 : 31;

  float4 I[6], s[6];
  bool yok[6];

  #pragma unroll
  for (int k=0;k<6;++k) {
    int gy = gy0 + R0 + k;
    yok[k] = ((unsigned)gy < (unsigned)H);
    float4 v = make_float4(PINF,PINF,PINF,PINF);
    if (yok[k] && xok) {
      size_t off = (size_t)gy*(W/4) + (gxb>>2);
      if (img < NB) {
        v = ((const float4*)targ)[(size_t)img*(HW/4)+off];
      } else {
        int b2 = img - NB;
        float4 p0 = ((const float4*)pred)[(size_t)(2*b2  )*(HW/4)+off];
        float4 p1 = ((const float4*)pred)[(size_t)(2*b2+1)*(HW/4)+off];
        v.x = 1.0f/(1.0f + __expf(p0.x - p1.x));
        v.y = 1.0f/(1.0f + __expf(p0.y - p1.y));
        v.z = 1.0f/(1.0f + __expf(p0.z - p1.z));
        v.w = 1.0f/(1.0f + __expf(p0.w - p1.w));
      }
    }
    I[k] = v;
  }

  #pragma unroll
  for (int u=0; u<11; ++u) {
    float4 h[6];
    #pragma unroll
    for (int k=0;k<6;++k) h[k] = hmin4(I[k]);
    shm.xch[0][2*g  ][j] = h[0];
    shm.xch[0][2*g+1][j] = h[5];
    float4 e[6];
    e[1]=vmin3(h[0],h[1],h[2]);
    e[2]=vmin3(h[1],h[2],h[3]);
    e[3]=vmin3(h[2],h[3],h[4]);
    e[4]=vmin3(h[3],h[4],h[5]);
    __syncthreads();
    float4 hm = shm.xch[0][ixm][j];
    float4 hp = shm.xch[0][ixp][j];
    e[0]=vmin3(hm  ,h[0],h[1]);
    e[5]=vmin3(h[4],h[5],hp  );

    float4 x[6];
    if (cwave) {
      if (allok) {
        #pragma unroll
        for (int k=0;k<6;++k) x[k] = hmax4(e[k]);
      } else {
        #pragma unroll
        for (int k=0;k<6;++k) x[k] = hmax4(msk4(e[k], xok && yok[k]));
      }
      shm.xch[1][2*g  ][j] = x[0];
      shm.xch[1][2*g+1][j] = x[5];
      #pragma unroll
      for (int k=1;k<5;++k) {
        float4 dl = vmax3(x[k-1], x[k], x[k+1]);
        float dx = fmaxf(I[k].x-dl.x,0.f), dy = fmaxf(I[k].y-dl.y,0.f);
        float dz = fmaxf(I[k].z-dl.z,0.f), dw = fmaxf(I[k].w-dl.w,0.f);
        if (u == 0) {
          s[k] = make_float4(dx,dy,dz,dw);
        } else {
          s[k].x += fmaxf(fmaf(-s[k].x, dx, dx), 0.f);
          s[k].y += fmaxf(fmaf(-s[k].y, dy, dy), 0.f);
          s[k].z += fmaxf(fmaf(-s[k].z, dz, dz), 0.f);
          s[k].w += fmaxf(fmaf(-s[k].w, dw, dw), 0.f);
        }
      }
    } else if (wid == 0) {
      float4 x5 = allok ? hmax4(e[5]) : hmax4(msk4(e[5], xok && yok[5]));
      shm.xch[1][2*g+1][j] = x5;
    } else {
      float4 x0 = allok ? hmax4(e[0]) : hmax4(msk4(e[0], xok && yok[0]));
      shm.xch[1][2*g  ][j] = x0;
    }
    __syncthreads();

    if (cwave) {
      float4 xm = shm.xch[1][2*g-1][j];
      float4 xp = shm.xch[1][2*g+2][j];
      #pragma unroll
      for (int k=0;k<6;k+=5) {
        float4 dl = (k==0) ? vmax3(xm, x[0], x[1]) : vmax3(x[4], x[5], xp);
        float dx = fmaxf(I[k].x-dl.x,0.f), dy = fmaxf(I[k].y-dl.y,0.f);
        float dz = fmaxf(I[k].z-dl.z,0.f), dw = fmaxf(I[k].w-dl.w,0.f);
        if (u == 0) {
          s[k] = make_float4(dx,dy,dz,dw);
        } else {
          s[k].x += fmaxf(fmaf(-s[k].x, dx, dx), 0.f);
          s[k].y += fmaxf(fmaf(-s[k].y, dy, dy), 0.f);
          s[k].z += fmaxf(fmaf(-s[k].z, dz, dz), 0.f);
          s[k].w += fmaxf(fmaf(-s[k].w, dw, dw), 0.f);
        }
      }
    }
    #pragma unroll
    for (int k=0;k<6;++k) I[k] = e[k];
  }

  if (cwave && cenj && gxb < W) {
    #pragma unroll
    for (int k=0;k<6;++k) {
      int gy = gy0 + R0 + k;
      if (gy < H)
        ((float4*)S)[(size_t)img*(HW/4) + (size_t)gy*(W/4) + (gxb>>2)] = s[k];
    }
  }

  // publish: flush stores, then release-count this tile (union also protected)
  __threadfence();
  __syncthreads();
  if (tid == 0)
    __hip_atomic_fetch_add(&done[img], 1u, __ATOMIC_RELEASE, __HIP_MEMORY_SCOPE_AGENT);
}

// ---------------- blur tile (round-16 body; tid<256 active) ----------------
__device__ __attribute__((noinline))
void blur_tile(int sx, int vh, int b, const float* __restrict__ Sin,
               double* __restrict__ sums, unsigned* __restrict__ cnt,
               float* __restrict__ out, ShmU& shm)
{
  const int tid = threadIdx.x;
  const int R0 = vh * 256;
  const float* G0 = Sin + (size_t)b*HW;
  const float* P0 = Sin + (size_t)(b+NB)*HW;

  const int pr = tid >> 4;
  const int pc = tid & 15;
  const int qg = sx*16 + pc;
  const int vg = tid >> 6;
  const int vc = tid & 63;

  double sgp = 0.0, sgg = 0.0, spp = 0.0;

#define HACC(val, idx)                                                      \
  { if ((idx)   >= 0 && (idx)   <= 50) a0 += (val) * GW[(idx)];             \
    if ((idx)-1 >= 0 && (idx)-1 <= 50) a1 += (val) * GW[(idx)-1];           \
    if ((idx)-2 >= 0 && (idx)-2 <= 50) a2 += (val) * GW[(idx)-2];           \
    if ((idx)-3 >= 0 && (idx)-3 <= 50) a3 += (val) * GW[(idx)-3]; }

#define HROW(SRC, DST, ROW)                                                 \
  { float a0=0.f, a1=0.f, a2=0.f, a3=0.f;                                   \
    if ((unsigned)(ROW) < (unsigned)H) {                                    \
      const float4* s4 = (const float4*)((SRC) + (size_t)(ROW)*W);          \
      _Pragma("unroll")                                                     \
      for (int coff = -7; coff <= 7; ++coff) {                              \
        int qq = qg + coff;                                                 \
        float4 v = make_float4(0.f,0.f,0.f,0.f);                            \
        if ((unsigned)qq < 256u) v = s4[qq];                                \
        const int base = 4*coff + 25;                                       \
        HACC(v.x, base+0) HACC(v.y, base+1) HACC(v.z, base+2) HACC(v.w, base+3) \
      }                                                                     \
    }                                                                       \
    float4 hv; hv.x=a0; hv.y=a1; hv.z=a2; hv.w=a3;                          \
    *(float4*)&DST[((ROW)+256)&127][4*pc] = hv; }

  if (tid < 256) {
    #pragma unroll
    for (int p = 0; p < 6; ++p) {
      int row = R0 - 39 + 16*p + pr;
      HROW(G0, shm.bd.hbg, row)
      HROW(P0, shm.bd.hbp, row)
    }
  }
  __syncthreads();

  for (int t = 0; t < 8; ++t) {
    const int R = R0 + 32*t;
    if (tid < 256) {
      {
        int ra = R + 57 + pr;
        int rb = R + 73 + pr;
        HROW(G0, shm.bd.hbg, ra)
        HROW(P0, shm.bd.hbp, ra)
        HROW(G0, shm.bd.hbg, rb)
        HROW(P0, shm.bd.hbp, rb)
      }
      {
        const int Rr = R + 8*vg;
        float ag[8] = {0,0,0,0,0,0,0,0}, ap[8] = {0,0,0,0,0,0,0,0};
        #pragma unroll
        for (int tt = 0; tt < 58; ++tt) {
          int idx = (Rr - 25 + tt + 256) & 127;
          float hg = shm.bd.hbg[idx][vc];
          float hp = shm.bd.hbp[idx][vc];
          #pragma unroll
          for (int jj = 0; jj < 8; ++jj) {
            int k = tt - jj;
            if (k >= 0 && k < KLEN) { ag[jj] += hg * GW[k]; ap[jj] += hp * GW[k]; }
          }
        }
        #pragma unroll
        for (int jj = 0; jj < 8; ++jj) {
          float a = fminf(fmaxf(ag[jj], 0.f), 1.f);
          float p = fminf(fmaxf(ap[jj], 0.f), 1.f);
          sgp += (double)(a*p); sgg += (double)(a*a); spp += (double)(p*p);
        }
      }
    }
    __syncthreads();
  }
#undef HROW
#undef HACC

  #pragma unroll
  for (int off = 32; off > 0; off >>= 1) {
    sgp += __shfl_down(sgp, off);
    sgg += __shfl_down(sgg, off);
    spp += __shfl_down(spp, off);
  }
  int lane = tid & 63, wv = tid >> 6;
  if (tid < 256 && lane == 0) { shm.bd.rbuf[wv] = sgp; shm.bd.rbuf[4+wv] = sgg; shm.bd.rbuf[8+wv] = spp; }
  __syncthreads();
  if (tid == 0) {
    double a  = shm.bd.rbuf[0]+shm.bd.rbuf[1]+shm.bd.rbuf[2]+shm.bd.rbuf[3];
    double g2 = shm.bd.rbuf[4]+shm.bd.rbuf[5]+shm.bd.rbuf[6]+shm.bd.rbuf[7];
    double p2 = shm.bd.rbuf[8]+shm.bd.rbuf[9]+shm.bd.rbuf[10]+shm.bd.rbuf[11];
    atomicAdd(&sums[b],      a);
    atomicAdd(&sums[NB+b],   g2);
    atomicAdd(&sums[2*NB+b], p2);
    __threadfence();
    unsigned dn = atomicAdd(cnt, 1u);
    if (dn == BLUR_BLOCKS - 1) {
      __threadfence();
      double acc = 0.0;
      for (int bb = 0; bb < NB; ++bb) {
        double num = 2.0*sums[bb] + 1e-6;
        double den = sums[NB+bb] + sums[2*NB+bb] + 1e-6;
        acc += 1.0 - num/den;
      }
      out[0] = (float)(acc / (double)NB);
    }
  }
  __syncthreads();   // protect rbuf (union) before any later skel Xch writes
}

// ---------------- persistent fused kernel ----------------
// 512 blocks (== 2/CU LDS capacity). Each block pops skel tiles from a global
// queue; between tiles checks whether its single blur tile's deps (done[b],
// done[b+NB] == 150) are met and, if so, runs it, then resumes popping. After
// the queue drains, remaining blocks spin-wait (safe: queue-empty => in-flight
// tiles finish on resident blocks => counters complete — deadlock-free
// regardless of dispatch order). Cross-XCD: release-add on done / acquire
// fence before reading S.
__global__ __launch_bounds__(512, 4)
void fused_kernel(const float* __restrict__ pred, const float* __restrict__ targ,
                  float* __restrict__ S, double* __restrict__ sums,
                  unsigned* __restrict__ cnt, unsigned* __restrict__ done,
                  unsigned* __restrict__ work, float* __restrict__ out)
{
  __shared__ ShmU shm;
  __shared__ int shflag;
  __shared__ unsigned shidx;

  const int tid = threadIdx.x;
  const int sx = blockIdx.x & 15;
  const int vh = (blockIdx.x >> 4) & 3;
  const int b  = blockIdx.x >> 6;
  bool blurDone = false;

  for (;;) {
    if (!blurDone) {
      if (tid == 0) {
        int r = (ldrlx(&done[b]) >= DONE_PER_IMG) &&
                (ldrlx(&done[b+NB]) >= DONE_PER_IMG);
        if (r) __threadfence();      // acquire: invalidate L1/L2 before S reads
        shflag = r;
      }
      __syncthreads();
      if (shflag) {
        blur_tile(sx, vh, b, S, sums, cnt, out, shm);
        blurDone = true;
      }
    }
    if (tid == 0) shidx = atomicAdd(work, 1u);
    __syncthreads();
    unsigned t = shidx;
    if (t >= SKEL_TILES) break;
    skel_tile((int)t, pred, targ, S, done, shm);
  }

  if (!blurDone) {
    if (tid == 0) {
      while (ldrlx(&done[b]) < DONE_PER_IMG || ldrlx(&done[b+NB]) < DONE_PER_IMG)
        __builtin_amdgcn_s_sleep(16);
      __threadfence();
    }
    __syncthreads();
    blur_tile(sx, vh, b, S, sums, cnt, out, shm);
  }
}

__global__ void zero_kernel(double* sums, unsigned* aux) {
  int t = threadIdx.x;
  if (t < 3*NB) sums[t] = 0.0;
  if (t < 18) aux[t] = 0u;     // cnt(1) + done(16) + work(1)
}

extern "C" void kernel_launch(void* const* d_in, const int* in_sizes, int n_in,
                              void* d_out, int out_size, void* d_ws, size_t ws_size,
                              hipStream_t stream)
{
  (void)in_sizes; (void)n_in; (void)out_size; (void)ws_size;
  const float* pred = (const float*)d_in[0];   // (8,2,1024,1024) f32
  const float* targ = (const float*)d_in[1];   // (8,1024,1024) f32
  float* out = (float*)d_out;

  float* Sbuf = (float*)d_ws;                        // 16*HW floats (skel)
  double* sums = (double*)(Sbuf + (size_t)NIMG*HW);  // 24 doubles
  unsigned* aux = (unsigned*)(sums + 3*NB);          // cnt, done[16], work
  unsigned* cnt  = aux;
  unsigned* done = aux + 1;
  unsigned* work = aux + 17;

  hipLaunchKernelGGL(zero_kernel, dim3(1), dim3(64), 0, stream, sums, aux);
  hipLaunchKernelGGL(fused_kernel, dim3(BLUR_BLOCKS), dim3(512), 0, stream,
                     pred, targ, Sbuf, sums, cnt, done, work, out);
}

// Round 18
// 201.744 us; speedup vs baseline: 4.7526x; 4.7526x over previous
//
#include <hip/hip_runtime.h>

// ---------------- problem constants ----------------
#define H 1024
#define W 1024
#define HW (H*W)
#define NB 8            // batch
#define NIMG 16         // gt batch (0..7) + pred-fg batch (8..15)
#define BORDER 25
#define KLEN 51

// Unnormalized Gaussian weights g[k] = exp(-(k-25)^2/200), k=0..50 (sigma=10).
__device__ __constant__ float GW[KLEN] = {
  0.04393693f, 0.05613476f, 0.07100535f, 0.08892162f, 0.11025053f,
  0.13533528f, 0.16447446f, 0.19789869f, 0.23574608f, 0.27803730f,
  0.32465247f, 0.37531110f, 0.42955736f, 0.48675226f, 0.54607442f,
  0.60653066f, 0.66697681f, 0.72614904f, 0.78270454f, 0.83527021f,
  0.88249690f, 0.92311635f, 0.95599748f, 0.98019867f, 0.99501248f,
  1.00000000f,
  0.99501248f, 0.98019867f, 0.95599748f, 0.92311635f, 0.88249690f,
  0.83527021f, 0.78270454f, 0.72614904f, 0.66697681f, 0.60653066f,
  0.54607442f, 0.48675226f, 0.42955736f, 0.37531110f, 0.32465247f,
  0.27803730f, 0.23574608f, 0.19789869f, 0.16447446f, 0.13533528f,
  0.11025053f, 0.08892162f, 0.07100535f, 0.05613476f, 0.04393693f
};

// Force single-instruction 3-input min/max (VOP3; all operands VGPR).
__device__ inline float m3n(float a,float b,float c){
  float d; asm("v_min3_f32 %0, %1, %2, %3" : "=v"(d) : "v"(a), "v"(b), "v"(c));
  return d;
}
__device__ inline float m3x(float a,float b,float c){
  float d; asm("v_max3_f32 %0, %1, %2, %3" : "=v"(d) : "v"(a), "v"(b), "v"(c));
  return d;
}

// Single-inst DPP wave shifts (bound_ctrl: OOB lane -> 0). The zeroed lane only
// corrupts buffer col 0 / col 127 — already invalid halo (12px budget).
__device__ inline float dpp_shr1(float x){   // lane i <- lane i-1
  return __int_as_float(__builtin_amdgcn_mov_dpp(__float_as_int(x), 0x138, 0xf, 0xf, true));
}
__device__ inline float dpp_shl1(float x){   // lane i <- lane i+1
  return __int_as_float(__builtin_amdgcn_mov_dpp(__float_as_int(x), 0x130, 0xf, 0xf, true));
}

__device__ inline float4 hmin4(float4 C){
  float Lw = dpp_shr1(C.w);
  float Rx = dpp_shl1(C.x);
  float4 h;
  h.x=m3n(Lw ,C.x,C.y); h.y=m3n(C.x,C.y,C.z);
  h.z=m3n(C.y,C.z,C.w); h.w=m3n(C.z,C.w,Rx );
  return h;
}
__device__ inline float4 hmax4(float4 C){
  float Lw = dpp_shr1(C.w);
  float Rx = dpp_shl1(C.x);
  float4 h;
  h.x=m3x(Lw ,C.x,C.y); h.y=m3x(C.x,C.y,C.z);
  h.z=m3x(C.y,C.z,C.w); h.w=m3x(C.z,C.w,Rx );
  return h;
}
__device__ inline float4 vmin3(float4 a,float4 b,float4 c){
  float4 o; o.x=m3n(a.x,b.x,c.x); o.y=m3n(a.y,b.y,c.y);
            o.z=m3n(a.z,b.z,c.z); o.w=m3n(a.w,b.w,c.w); return o;
}
__device__ inline float4 vmax3(float4 a,float4 b,float4 c){
  float4 o; o.x=m3x(a.x,b.x,c.x); o.y=m3x(a.y,b.y,c.y);
            o.z=m3x(a.z,b.z,c.z); o.w=m3x(a.w,b.w,c.w); return o;
}
__device__ inline float4 msk4(float4 e, bool v){
  constexpr float NINF = -__builtin_huge_valf();
  float4 o; o.x=v?e.x:NINF; o.y=v?e.y:NINF; o.z=v?e.z:NINF; o.w=v?e.w:NINF;
  return o;
}

// Single-launch register-resident fused skeletonize: all 11 units (unrolled).
// Buffer: 32 f4 (128 px) x 96 rows; center px/rows [12,116)x[12,84) -> 104x72.
// 512 threads = 16 groups x 32 lanes; group g owns rows [6g, 6g+6) in regs.
// Waves 1-6 own exactly the center rows [12,84): only they run dilate/delta/
// skel-update; waves 0/7 contribute just the boundary dilate row neighbors read.
// Barrier-slack scheduling: only e/dil rows 0 and 5 depend on exchanged data,
// so interior rows (1-4) are computed BETWEEN the Xch write and the barrier.
// Unit u: I_{u+1}=erode(I_u); delta=relu(I_u - dilate(mask(I_{u+1})));
// s += relu(d - s*d) (s=d at u=0). +inf padding == valid-only min; mask makes
// dilate valid-only (exact vs reference). 11 erodes + 1 dilate = 12 px <= halo 12.
__global__ __launch_bounds__(512, 3)
void skel11_kernel(const float* __restrict__ pred, const float* __restrict__ targ,
                   float* __restrict__ S, double* __restrict__ sums,
                   unsigned* __restrict__ cnt)
{
  constexpr float PINF = __builtin_huge_valf();
  __shared__ float4 Xch[2][32][32];   // [slot][2 boundary rows x 16 groups][f4 col]

  const int img = blockIdx.z;
  const int bx = blockIdx.x, by = blockIdx.y;

  // fold zero_sums + counter reset into this kernel (consumed by later kernels)
  if (bx==0 && by==0 && img==0) {
    if (threadIdx.x < 3*NB) sums[threadIdx.x] = 0.0;
    if (threadIdx.x == 3*NB) cnt[0] = 0u;
  }

  const int gx0 = bx*104 - 12, gy0 = by*72 - 12;
  const int tid = threadIdx.x;
  const int g = tid >> 5;             // 16 row-groups
  const int j = tid & 31;             // f4-col
  const int wid = tid >> 6;           // wave 0..7
  const int R0 = 6*g;
  const int gxb = gx0 + 4*j;
  const bool xok = ((unsigned)gxb < (unsigned)W);
  const bool cenj = (j >= 3) && (j < 29);
  const bool allok = (gx0 >= 0) && (gx0 + 128 <= W) && (gy0 >= 0) && (gy0 + 96 <= H);
  const bool cwave = (wid >= 1) && (wid <= 6);   // rows 6g+k all in [12,84)

  // clamped exchange indices (clamped slot == own boundary row == fallback)
  const int ixm = (g>0)  ? 2*g-1 : 0;
  const int ixp = (g<15) ? 2*g+2 : 31;

  float4 I[6], s[6];
  bool yok[6];

  // ---- load 6 rows (OOB = +inf, the min identity); softmax fg for imgs 8-15 ----
  #pragma unroll
  for (int k=0;k<6;++k) {
    int gy = gy0 + R0 + k;
    yok[k] = ((unsigned)gy < (unsigned)H);
    float4 v = make_float4(PINF,PINF,PINF,PINF);
    if (yok[k] && xok) {
      size_t off = (size_t)gy*(W/4) + (gxb>>2);
      if (img < NB) {
        v = ((const float4*)targ)[(size_t)img*(HW/4)+off];
      } else {
        int b2 = img - NB;
        float4 p0 = ((const float4*)pred)[(size_t)(2*b2  )*(HW/4)+off];
        float4 p1 = ((const float4*)pred)[(size_t)(2*b2+1)*(HW/4)+off];
        v.x = 1.0f/(1.0f + __expf(p0.x - p1.x));
        v.y = 1.0f/(1.0f + __expf(p0.y - p1.y));
        v.z = 1.0f/(1.0f + __expf(p0.z - p1.z));
        v.w = 1.0f/(1.0f + __expf(p0.w - p1.w));
      }
    }
    I[k] = v;
  }

  #pragma unroll
  for (int u=0; u<11; ++u) {
    // ---- erode: H-min via DPP; write exchange; interior V-min before barrier ----
    float4 h[6];
    #pragma unroll
    for (int k=0;k<6;++k) h[k] = hmin4(I[k]);
    Xch[0][2*g  ][j] = h[0];
    Xch[0][2*g+1][j] = h[5];
    float4 e[6];
    e[1]=vmin3(h[0],h[1],h[2]);       // interior rows: no exchanged data needed
    e[2]=vmin3(h[1],h[2],h[3]);
    e[3]=vmin3(h[2],h[3],h[4]);
    e[4]=vmin3(h[3],h[4],h[5]);
    __syncthreads();
    float4 hm = Xch[0][ixm][j];
    float4 hp = Xch[0][ixp][j];
    e[0]=vmin3(hm  ,h[0],h[1]);
    e[5]=vmin3(h[4],h[5],hp  );

    // ---- dilate of masked I_{u+1}: full on waves 1-6, boundary row on 0/7;
    //      interior delta/skel (k=1..4) before the barrier ----
    float4 x[6];
    if (cwave) {
      if (allok) {
        #pragma unroll
        for (int k=0;k<6;++k) x[k] = hmax4(e[k]);
      } else {
        #pragma unroll
        for (int k=0;k<6;++k) x[k] = hmax4(msk4(e[k], xok && yok[k]));
      }
      Xch[1][2*g  ][j] = x[0];
      Xch[1][2*g+1][j] = x[5];
      #pragma unroll
      for (int k=1;k<5;++k) {         // interior rows: all x local
        float4 dl = vmax3(x[k-1], x[k], x[k+1]);
        float dx = fmaxf(I[k].x-dl.x,0.f), dy = fmaxf(I[k].y-dl.y,0.f);
        float dz = fmaxf(I[k].z-dl.z,0.f), dw = fmaxf(I[k].w-dl.w,0.f);
        if (u == 0) {
          s[k] = make_float4(dx,dy,dz,dw);
        } else {
          s[k].x += fmaxf(fmaf(-s[k].x, dx, dx), 0.f);
          s[k].y += fmaxf(fmaf(-s[k].y, dy, dy), 0.f);
          s[k].z += fmaxf(fmaf(-s[k].z, dz, dz), 0.f);
          s[k].w += fmaxf(fmaf(-s[k].w, dw, dw), 0.f);
        }
      }
    } else if (wid == 0) {      // neighbors read only group1 row5 (Xch[1][3])
      float4 x5 = allok ? hmax4(e[5]) : hmax4(msk4(e[5], xok && yok[5]));
      Xch[1][2*g+1][j] = x5;
    } else {                    // wid==7: neighbors read only group14 row0 (Xch[1][28])
      float4 x0 = allok ? hmax4(e[0]) : hmax4(msk4(e[0], xok && yok[0]));
      Xch[1][2*g  ][j] = x0;
    }
    __syncthreads();

    // ---- boundary delta rows (k=0,5) need exchanged x ----
    if (cwave) {
      float4 xm = Xch[1][2*g-1][j];   // g in [2,13]: indices always valid
      float4 xp = Xch[1][2*g+2][j];
      #pragma unroll
      for (int k=0;k<6;k+=5) {
        float4 dl = (k==0) ? vmax3(xm, x[0], x[1]) : vmax3(x[4], x[5], xp);
        float dx = fmaxf(I[k].x-dl.x,0.f), dy = fmaxf(I[k].y-dl.y,0.f);
        float dz = fmaxf(I[k].z-dl.z,0.f), dw = fmaxf(I[k].w-dl.w,0.f);
        if (u == 0) {
          s[k] = make_float4(dx,dy,dz,dw);
        } else {
          s[k].x += fmaxf(fmaf(-s[k].x, dx, dx), 0.f);
          s[k].y += fmaxf(fmaf(-s[k].y, dy, dy), 0.f);
          s[k].z += fmaxf(fmaf(-s[k].z, dz, dz), 0.f);
          s[k].w += fmaxf(fmaf(-s[k].w, dw, dw), 0.f);
        }
      }
    }
    #pragma unroll
    for (int k=0;k<6;++k) I[k] = e[k];
  }

  // ---- write back skel (waves 1-6, center cols, clipped to image) ----
  if (cwave && cenj && gxb < W) {
    #pragma unroll
    for (int k=0;k<6;++k) {
      int gy = gy0 + R0 + k;        // rows 12..83 of buffer -> gy >= 0
      if (gy < H)
        ((float4*)S)[(size_t)img*(HW/4) + (size_t)gy*(W/4) + (gxb>>2)] = s[k];
    }
  }
}

// -------- fused H-blur + V-blur + clip + soft-dice, no intermediate --------
// Block = 64-col strip x 256 output rows x one (gt,pr) pair, 8 chunks x 32 rows.
// 512 blocks (2/CU). H-blurred rows live in a 128-row LDS ring per image.
// Per 32-row chunk, ALL threads first H-blur the next 32 rows [R+57,R+88]
// (2 rows x 2 img each), then V-blur+dice 8 rows/thread (64 cols x 4 groups),
// then ONE barrier. Alias safety: H(t) writes [R+57,R+88] vs V(t) reads
// [R-25,R+56]: row diff in [1,113], never 0 mod 128. Prologue fills
// [R0-39, R0+56] (6 passes). Round-15 lesson: keep ONE uniform code path
// (edge/interior template split cost +37 us). Round-17 lesson: persistent
// fusion spills and serializes — two-kernel pipeline is the sweet spot.
// Zero-padding both axes == conv SAME. Last finished block computes the loss.
#define NVB (16*4*NB)   // 512 blocks
__global__ __launch_bounds__(256, 2)
void blurdice_kernel(const float* __restrict__ Sin, double* __restrict__ sums,
                     unsigned* __restrict__ cnt, float* __restrict__ out)
{
  __shared__ float HbG[128][64];    // 32 KB
  __shared__ float HbP[128][64];    // 32 KB
  __shared__ double rbuf[12];

  const int sx = blockIdx.x;        // strip (64 cols)
  const int vh = blockIdx.y;        // vertical quarter (256 rows)
  const int b  = blockIdx.z;        // image pair
  const int tid = threadIdx.x;
  const int R0 = vh * 256;

  const float* G0 = Sin + (size_t)b*HW;
  const float* P0 = Sin + (size_t)(b+NB)*HW;

  // H mapping: 16 rows x 16 f4-colgroups
  const int pr = tid >> 4;
  const int pc = tid & 15;
  const int qg = sx*16 + pc;        // global f4 col produced

  // V mapping: 4 row-groups x 64 cols
  const int vg = tid >> 6;
  const int vc = tid & 63;

  double sgp = 0.0, sgg = 0.0, spp = 0.0;

#define HACC(val, idx)                                                      \
  { if ((idx)   >= 0 && (idx)   <= 50) a0 += (val) * GW[(idx)];             \
    if ((idx)-1 >= 0 && (idx)-1 <= 50) a1 += (val) * GW[(idx)-1];           \
    if ((idx)-2 >= 0 && (idx)-2 <= 50) a2 += (val) * GW[(idx)-2];           \
    if ((idx)-3 >= 0 && (idx)-3 <= 50) a3 += (val) * GW[(idx)-3]; }

#define HROW(SRC, DST, ROW)                                                 \
  { float a0=0.f, a1=0.f, a2=0.f, a3=0.f;                                   \
    if ((unsigned)(ROW) < (unsigned)H) {                                    \
      const float4* s4 = (const float4*)((SRC) + (size_t)(ROW)*W);          \
      _Pragma("unroll")                                                     \
      for (int coff = -7; coff <= 7; ++coff) {                              \
        int qq = qg + coff;                                                 \
        float4 v = make_float4(0.f,0.f,0.f,0.f);                            \
        if ((unsigned)qq < 256u) v = s4[qq];                                \
        const int base = 4*coff + 25;                                       \
        HACC(v.x, base+0) HACC(v.y, base+1) HACC(v.z, base+2) HACC(v.w, base+3) \
      }                                                                     \
    }                                                                       \
    float4 hv; hv.x=a0; hv.y=a1; hv.z=a2; hv.w=a3;                          \
    *(float4*)&DST[((ROW)+256)&127][4*pc] = hv; }

  // ---- prologue: fill ring rows [R0-39, R0+56] (6 passes) ----
  #pragma unroll
  for (int p = 0; p < 6; ++p) {
    int row = R0 - 39 + 16*p + pr;
    HROW(G0, HbG, row)
    HROW(P0, HbP, row)
  }
  __syncthreads();

  for (int t = 0; t < 8; ++t) {
    const int R = R0 + 32*t;
    // ---- H: produce rows [R+57, R+88] (not read by V(t)) ----
    {
      int ra = R + 57 + pr;
      int rb = R + 73 + pr;
      HROW(G0, HbG, ra)
      HROW(P0, HbP, ra)
      HROW(G0, HbG, rb)
      HROW(P0, HbP, rb)
    }
    // ---- V + dice: output rows R+8vg .. R+8vg+7 (58-row sliding window) ----
    {
      const int Rr = R + 8*vg;
      float ag[8] = {0,0,0,0,0,0,0,0}, ap[8] = {0,0,0,0,0,0,0,0};
      #pragma unroll
      for (int tt = 0; tt < 58; ++tt) {
        int idx = (Rr - 25 + tt + 256) & 127;
        float hg = HbG[idx][vc];
        float hp = HbP[idx][vc];
        #pragma unroll
        for (int jj = 0; jj < 8; ++jj) {
          int k = tt - jj;
          if (k >= 0 && k < KLEN) { ag[jj] += hg * GW[k]; ap[jj] += hp * GW[k]; }
        }
      }
      #pragma unroll
      for (int jj = 0; jj < 8; ++jj) {
        float a = fminf(fmaxf(ag[jj], 0.f), 1.f);
        float p = fminf(fmaxf(ap[jj], 0.f), 1.f);
        sgp += (double)(a*p); sgg += (double)(a*a); spp += (double)(p*p);
      }
    }
    __syncthreads();   // H(t) writes complete before V(t+1) reads
  }
#undef HROW
#undef HACC

  // ---- block reduction + atomics + last-block finalize ----
  #pragma unroll
  for (int off = 32; off > 0; off >>= 1) {
    sgp += __shfl_down(sgp, off);
    sgg += __shfl_down(sgg, off);
    spp += __shfl_down(spp, off);
  }
  int lane = tid & 63, wv = tid >> 6;
  if (lane == 0) { rbuf[wv] = sgp; rbuf[4+wv] = sgg; rbuf[8+wv] = spp; }
  __syncthreads();
  if (tid == 0) {
    double a  = rbuf[0]+rbuf[1]+rbuf[2]+rbuf[3];
    double g2 = rbuf[4]+rbuf[5]+rbuf[6]+rbuf[7];
    double p2 = rbuf[8]+rbuf[9]+rbuf[10]+rbuf[11];
    atomicAdd(&sums[b],      a);
    atomicAdd(&sums[NB+b],   g2);
    atomicAdd(&sums[2*NB+b], p2);
    __threadfence();
    unsigned done = atomicAdd(cnt, 1u);
    if (done == NVB - 1) {               // last block: fold the final reduction
      __threadfence();
      double acc = 0.0;
      for (int bb = 0; bb < NB; ++bb) {
        double num = 2.0*sums[bb] + 1e-6;
        double den = sums[NB+bb] + sums[2*NB+bb] + 1e-6;
        acc += 1.0 - num/den;
      }
      out[0] = (float)(acc / (double)NB);
    }
  }
}

extern "C" void kernel_launch(void* const* d_in, const int* in_sizes, int n_in,
                              void* d_out, int out_size, void* d_ws, size_t ws_size,
                              hipStream_t stream)
{
  (void)in_sizes; (void)n_in; (void)out_size; (void)ws_size;
  const float* pred = (const float*)d_in[0];   // (8,2,1024,1024) f32
  const float* targ = (const float*)d_in[1];   // (8,1024,1024) f32
  float* out = (float*)d_out;

  float* Sbuf = (float*)d_ws;                        // 16*HW floats (skel)
  double* sums = (double*)(Sbuf + (size_t)NIMG*HW);  // 24 doubles
  unsigned* cnt = (unsigned*)(sums + 3*NB);          // completion counter

  // all 11 skeletonize units in one launch (center 104x72 per block); zeroes sums+cnt
  hipLaunchKernelGGL(skel11_kernel, dim3(10, 15, NIMG), dim3(512), 0, stream,
                     pred, targ, Sbuf, sums, cnt);
  // fused Gaussian border (H+V) + dice partial sums + final loss
  hipLaunchKernelGGL(blurdice_kernel, dim3(16, 4, NB), dim3(256), 0, stream,
                     Sbuf, sums, cnt, out);
}